// Round 10
// baseline (83.722 us; speedup 1.0000x reference)
//
#include <hip/hip_runtime.h>
#include <hip/hip_bf16.h>
#include <math.h>

typedef unsigned int u32;
typedef unsigned short u16;
typedef __bf16 bf16_t;
typedef bf16_t bf16x8 __attribute__((ext_vector_type(8)));
typedef float f32x4 __attribute__((ext_vector_type(4)));

#define B_N 8192
#define D_K 256
#define NCLS 360
#define NG 64                 // 64 groups of 128 rows; upper-tri pairs = 2080
#define NBLK 2080
#define NPART 64              // partials per row in k_final
#define MAXC 61

#define SCALE2 (-20.609929155556627f)   // -(1/0.07)*log2(e)
#define LN2 (0.6931471805599453f)
#define INV_T (14.285714285714286f)     // 1/0.07

__device__ __forceinline__ float fexp2(float x) { return __builtin_amdgcn_exp2f(x); }

__device__ __forceinline__ u16 f2bf(float x) {
  u32 u = __float_as_uint(x);
  u32 r = (u + 0x7fffu + ((u >> 16) & 1u)) >> 16;
  return (u16)r;
}

__device__ __forceinline__ void gl_lds16(const void* g, void* l) {
  __builtin_amdgcn_global_load_lds(
      (const __attribute__((address_space(1))) u32*)g,
      (__attribute__((address_space(3))) u32*)l, 16, 0, 0);
}

// ---------------- K1: convert f32 -> bf16; zero the output accumulator
__global__ void k_prep(const float* __restrict__ f, u16* __restrict__ fbf,
                       float* __restrict__ out) {
  if (blockIdx.x == 0 && threadIdx.x == 0) out[0] = 0.f;
  int t = blockIdx.x * 256 + threadIdx.x;
  int e4 = t * 4;
  const float4 v = *reinterpret_cast<const float4*>(f + e4);
  ushort4 b;
  b.x = f2bf(v.x); b.y = f2bf(v.y); b.z = f2bf(v.z); b.w = f2bf(v.w);
  *reinterpret_cast<ushort4*>(fbf + e4) = b;
}

// ---------------- K2: symmetric Gram — one 128x128 tile pair (i<=j) per block
// Row-pass covers rows of group i over cols of group j; col-pass (transpose)
// covers rows of group j over cols of group i. Diagonal: row-pass only.
__global__ __launch_bounds__(256, 2) void k_main(const u16* __restrict__ fb,
                                                 float2* __restrict__ part) {
  __shared__ __align__(16) u16 Bs[128 * D_K];   // 64KB B-tile
  __shared__ float2 colred[4][128];             // 4KB col-pass cross-wave merge

  const int tid = threadIdx.x;
  const int lane = tid & 63;
  const int w = tid >> 6;
  const int t15 = lane & 15;
  const int g = lane >> 4;
  const int t7 = t15 & 7;

  // decode upper-triangular pair (i <= j) from blockIdx
  const int bid = blockIdx.x;
#define TRI(x) ((x) * NG - ((x) * ((x)-1)) / 2)
  int i = (int)((129.0 - sqrt(129.0 * 129.0 - 8.0 * (double)bid)) * 0.5);
  i = i < 0 ? 0 : (i > NG - 1 ? NG - 1 : i);
  while (TRI(i + 1) <= bid) ++i;
  while (TRI(i) > bid) --i;
  const int j = i + (bid - TRI(i));
  const int rowbase = i * 128 + w * 32;
  const int colb = j * 128;

  // stage B tile (128 cols x 256 K, bf16, 64KB), pre-swizzled source chunks
#pragma unroll
  for (int it = 0; it < 16; ++it) {
    int lin = (w * 16 + it) * 1024 + lane * 16;  // byte offset in 64KB tile
    int row = lin >> 9;                           // 512B per row
    int c = (lin >> 4) & 31;                      // 16B chunk in row
    int q = c ^ (row & 7);                        // pre-swizzled source chunk
    gl_lds16(fb + (size_t)(colb + row) * D_K + q * 8, &Bs[0] + (w * 16 + it) * 512);
  }

  // A fragments: 32 rows x 256 K per wave, register resident
  bf16x8 A[2][8];
#pragma unroll
  for (int rs = 0; rs < 2; ++rs)
#pragma unroll
    for (int kk = 0; kk < 8; ++kk) {
      const u16* p = fb + (size_t)(rowbase + rs * 16 + t15) * D_K + kk * 32 + g * 8;
      A[rs][kk] = *reinterpret_cast<const bf16x8*>(p);
    }

  __syncthreads();  // B tile resident

  // ds_read base decomposition (chunk q = (kk*4+g)^t7)
  const int gl8 = (g ^ (t7 & 3)) * 8;
  const int b2 = (t7 >> 2) & 1;
  const int offE = t15 * 256 + gl8 + b2 * 32;        // kk even
  const int offO = t15 * 256 + gl8 + (b2 ^ 1) * 32;  // kk odd

  const f32x4 z4 = {0.f, 0.f, 0.f, 0.f};
  f32x4 C[2][8];
#pragma unroll
  for (int kk = 0; kk < 8; ++kk) {
    bf16x8 Bf[8];
    const u16* ba = &Bs[0] + ((kk & 1) ? offO : offE) + (kk >> 1) * 64;
#pragma unroll
    for (int s = 0; s < 8; ++s)
      Bf[s] = *reinterpret_cast<const bf16x8*>(ba + s * 4096);
#pragma unroll
    for (int rs = 0; rs < 2; ++rs)
#pragma unroll
      for (int s = 0; s < 8; ++s)
        C[rs][s] = __builtin_amdgcn_mfma_f32_16x16x32_bf16(
            A[rs][kk], Bf[s], (kk == 0) ? z4 : C[rs][s], 0, 0, 0);
  }

  // ---- row-pass: per slot (rs,q) reduce over 8 col fragments + t15 lanes
#pragma unroll
  for (int rs = 0; rs < 2; ++rs) {
#pragma unroll
    for (int q = 0; q < 4; ++q) {
      float v0 = C[rs][0][q], v1 = C[rs][1][q], v2 = C[rs][2][q], v3 = C[rs][3][q];
      float v4 = C[rs][4][q], v5 = C[rs][5][q], v6 = C[rs][6][q], v7 = C[rs][7][q];
      float m = fminf(fminf(fminf(v0, v1), fminf(v2, v3)),
                      fminf(fminf(v4, v5), fminf(v6, v7)));  // min dot = max logit
      float mL = m * SCALE2;
      float e = ((fexp2(fmaf(v0, SCALE2, -mL)) + fexp2(fmaf(v1, SCALE2, -mL))) +
                 (fexp2(fmaf(v2, SCALE2, -mL)) + fexp2(fmaf(v3, SCALE2, -mL)))) +
                ((fexp2(fmaf(v4, SCALE2, -mL)) + fexp2(fmaf(v5, SCALE2, -mL))) +
                 (fexp2(fmaf(v6, SCALE2, -mL)) + fexp2(fmaf(v7, SCALE2, -mL))));
#pragma unroll
      for (int st = 1; st < 16; st <<= 1) {
        float om = __shfl_xor(mL, st);
        float oe = __shfl_xor(e, st);
        float nm = fmaxf(mL, om);
        e = e * fexp2(mL - nm) + oe * fexp2(om - nm);
        mL = nm;
      }
      if (t15 == 0)
        part[(size_t)j * B_N + rowbase + rs * 16 + g * 4 + q] = make_float2(mL, e);
    }
  }

  // ---- col-pass (transpose rows): skip on diagonal (row-pass covered it)
  if (i != j) {
#pragma unroll
    for (int s = 0; s < 8; ++s) {
      float v0 = C[0][s][0], v1 = C[0][s][1], v2 = C[0][s][2], v3 = C[0][s][3];
      float v4 = C[1][s][0], v5 = C[1][s][1], v6 = C[1][s][2], v7 = C[1][s][3];
      float m = fminf(fminf(fminf(v0, v1), fminf(v2, v3)),
                      fminf(fminf(v4, v5), fminf(v6, v7)));
      m = fminf(m, __shfl_xor(m, 16));
      m = fminf(m, __shfl_xor(m, 32));
      float mL = m * SCALE2;
      float e = ((fexp2(fmaf(v0, SCALE2, -mL)) + fexp2(fmaf(v1, SCALE2, -mL))) +
                 (fexp2(fmaf(v2, SCALE2, -mL)) + fexp2(fmaf(v3, SCALE2, -mL)))) +
                ((fexp2(fmaf(v4, SCALE2, -mL)) + fexp2(fmaf(v5, SCALE2, -mL))) +
                 (fexp2(fmaf(v6, SCALE2, -mL)) + fexp2(fmaf(v7, SCALE2, -mL))));
      e += __shfl_xor(e, 16);
      e += __shfl_xor(e, 32);
      if (g == 0) colred[w][s * 16 + t15] = make_float2(mL, e);
    }
    __syncthreads();
    if (tid < 128) {
      float2 p = colred[0][tid];
      float m = p.x, e = p.y;
#pragma unroll
      for (int ww = 1; ww < 4; ++ww) {
        float2 o = colred[ww][tid];
        float nm = fmaxf(m, o.x);
        e = e * fexp2(m - nm) + o.y * fexp2(o.x - nm);
        m = nm;
      }
      part[(size_t)i * B_N + colb + tid] = make_float2(m, e);
    }
  }
}

// ---------------- K3: per-class exact fp32 Gram -> Ep, sum positive dots, loss
__global__ __launch_bounds__(256) void k_final(const float* __restrict__ f,
                                               const int* __restrict__ lab,
                                               const float2* __restrict__ part,
                                               float* __restrict__ out) {
  __shared__ __align__(16) float4 feat[MAXC][65];  // padded, conflict-free
  __shared__ float m2a[MAXC], Eaa[MAXC], Epa[MAXC], sda[MAXC];
  __shared__ int idx[MAXC];
  __shared__ int nS;
  const int c = blockIdx.x;
  const int tid = threadIdx.x;
  const int lane = tid & 63;
  const int w = tid >> 6;
  if (tid == 0) nS = 0;
  __syncthreads();

  for (int i = tid; i < B_N / 4; i += 256) {
    const int4 lv = reinterpret_cast<const int4*>(lab)[i];
    if (lv.x == c) { int p = atomicAdd(&nS, 1); if (p < MAXC) idx[p] = i * 4 + 0; }
    if (lv.y == c) { int p = atomicAdd(&nS, 1); if (p < MAXC) idx[p] = i * 4 + 1; }
    if (lv.z == c) { int p = atomicAdd(&nS, 1); if (p < MAXC) idx[p] = i * 4 + 2; }
    if (lv.w == c) { int p = atomicAdd(&nS, 1); if (p < MAXC) idx[p] = i * 4 + 3; }
  }
  __syncthreads();
  const int n = nS < MAXC ? nS : MAXC;

  for (int j = w; j < n; j += 4)
    feat[j][lane] = reinterpret_cast<const float4*>(f + (size_t)idx[j] * D_K)[lane];

  // merge the 64 partials per row (one per lane), 6-step xor merge
  for (int j = w; j < n; j += 4) {
    float2 p = part[(size_t)lane * B_N + idx[j]];
    float m2 = p.x, Ea = p.y;
#pragma unroll
    for (int st = 1; st < NPART; st <<= 1) {
      float om = __shfl_xor(m2, st);
      float oa = __shfl_xor(Ea, st);
      float nm = fmaxf(m2, om);
      Ea = Ea * fexp2(m2 - nm) + oa * fexp2(om - nm);
      m2 = nm;
    }
    if (lane == 0) { m2a[j] = m2; Eaa[j] = Ea; Epa[j] = 0.f; sda[j] = 0.f; }
  }
  __syncthreads();

  const int ntile = (n + 7) >> 3;
  const int jj = lane >> 3, kk = lane & 7;
  for (int tile = w; tile < ntile * ntile; tile += 4) {
    const int j = (tile / ntile) * 8 + jj;
    const int k = (tile % ntile) * 8 + kk;
    const bool ok = (j < n) && (k < n) && (j != k);
    const int jc = j < n ? j : 0, kc = k < n ? k : 0;
    f32x4 acc = {0.f, 0.f, 0.f, 0.f};
#pragma unroll 8
    for (int d = 0; d < 64; ++d) {
      const float4 a = feat[jc][d];
      const float4 b = feat[kc][d];
      acc[0] = fmaf(a.x, b.x, acc[0]);
      acc[1] = fmaf(a.y, b.y, acc[1]);
      acc[2] = fmaf(a.z, b.z, acc[2]);
      acc[3] = fmaf(a.w, b.w, acc[3]);
    }
    float dot = ok ? ((acc[0] + acc[1]) + (acc[2] + acc[3])) : 0.f;
    float ex = ok ? fexp2(fmaf(dot, SCALE2, -m2a[jc])) : 0.f;
#pragma unroll
    for (int st = 1; st < 8; st <<= 1) {
      dot += __shfl_xor(dot, st);
      ex += __shfl_xor(ex, st);
    }
    if (kk == 0 && j < n) {
      atomicAdd(&sda[j], dot);
      atomicAdd(&Epa[j], ex);
    }
  }
  __syncthreads();

  if (w == 0) {
    float contrib = 0.f;
    if (lane < n) {
      const int j = lane;
      float m2 = m2a[j], Ea = Eaa[j], Ep = Epa[j], sumdot = sda[j];
      float En = fmaxf(Ea - Ep, 0.f);         // self term underflows
      int cntp = n - 1;
      float cntn = (float)(B_N - 1 - cntp);
      float denom = Ep + En / (cntn + 1e-8f);
      float Sadc = -sumdot * INV_T;           // exact fp32 sum of positive logits
      float num = Sadc - (float)cntp * (m2 * LN2) - (float)cntp * logf(denom);
      float dv = (cntp <= 0) ? 1.f : (float)cntp;
      contrib = num / dv;
    }
#pragma unroll
    for (int st = 1; st < 64; st <<= 1) contrib += __shfl_xor(contrib, st);
    if (lane == 0) atomicAdd(out, contrib * (1.f / (float)B_N));
  }
}

extern "C" void kernel_launch(void* const* d_in, const int* in_sizes, int n_in,
                              void* d_out, int out_size, void* d_ws, size_t ws_size,
                              hipStream_t stream) {
  const float* f = (const float*)d_in[0];
  const int* lab = (const int*)d_in[1];

  char* ws = (char*)d_ws;
  u16* fbf = (u16*)ws;                        // 4 MB
  float2* part = (float2*)(ws + 4194304);     // 64*8192*8 = 4 MB

  k_prep<<<2048, 256, 0, stream>>>(f, fbf, (float*)d_out);
  k_main<<<NBLK, 256, 0, stream>>>(fbf, part);
  k_final<<<NCLS, 256, 0, stream>>>(f, lab, part, (float*)d_out);
}